// Round 13
// baseline (316.091 us; speedup 1.0000x reference)
//
#include <hip/hip_runtime.h>
#include <math.h>

#define N_NODES 50000
#define N_ROWS_PAD 50048   // 782 * 64
#define N_GRAPHS 500
#define NPG 100
#define N_EDGES 500000
#define F_IN 16
#define HID 64
#define EW_CAP 1408        // max intra-graph edges (mean 1000, sigma ~32 -> +12.9 sigma)

#define SELU_SCALE 1.0507009873554804934193349852946f
#define SELU_ALPHA 1.6732632423543772848170429916717f

typedef __attribute__((ext_vector_type(8))) short short8;
typedef __attribute__((ext_vector_type(8))) unsigned short ushort8;
typedef __attribute__((ext_vector_type(4))) float floatx4;

__device__ __forceinline__ float lrelu(float x){ return x > 0.f ? x : 0.2f * x; }
__device__ __forceinline__ float eluf(float x){ return x > 0.f ? x : expf(x) - 1.f; }
__device__ __forceinline__ float seluf(float x){
    return x > 0.f ? SELU_SCALE * x : SELU_SCALE * (SELU_ALPHA * (expf(x) - 1.f));
}
__device__ __forceinline__ unsigned short f2bf(float x){
    unsigned u = __float_as_uint(x);
    return (unsigned short)((u + 0x7FFFu + ((u >> 16) & 1u)) >> 16);
}
__device__ __forceinline__ float bf2f(unsigned short u){
    return __uint_as_float((unsigned)u << 16);
}
__device__ __forceinline__ float bf2f_lo(unsigned u){
    return __uint_as_float(u << 16);
}
__device__ __forceinline__ float bf2f_hi(unsigned u){
    return __uint_as_float(u & 0xFFFF0000u);
}

// ---------------- CSR build (slab format, graph-local offsets) ----------------
__global__ void k_count(const int* __restrict__ dst, int* __restrict__ counts){
    int e = blockIdx.x * 256 + threadIdx.x;
    if (e < N_EDGES) atomicAdd(&counts[dst[e]], 1);
}

__global__ void __launch_bounds__(128)
k_local_scan(const int* __restrict__ counts, int* __restrict__ noff,
             int* __restrict__ cnt, int* __restrict__ write_ptr){
    __shared__ int s[128];
    int g = blockIdx.x, t = threadIdx.x;
    int v = (t < NPG) ? counts[g * NPG + t] : 0;
    s[t] = v; __syncthreads();
    for (int o = 1; o < 128; o <<= 1){
        int x = (t >= o) ? s[t - o] : 0;
        __syncthreads();
        s[t] += x;
        __syncthreads();
    }
    if (t < NPG){
        int excl = s[t] - v;
        noff[g * NPG + t] = excl;     // graph-local exclusive offset
        cnt[g * NPG + t] = v;
        write_ptr[g * NPG + t] = excl;
    }
}

__global__ void k_scatter(const int* __restrict__ src, const int* __restrict__ dst,
                          int* __restrict__ write_ptr, unsigned* __restrict__ csr){
    int e = blockIdx.x * 256 + threadIdx.x;
    if (e < N_EDGES){
        int d = dst[e];
        int g = d / NPG;
        int b = g * NPG;
        int pos = atomicAdd(&write_ptr[d], 1);
        csr[(size_t)g * EW_CAP + pos] = (unsigned)((src[e] - b) | ((d - b) << 8));
    }
}

// ---------------- prep: weight packs + logit matrices ----------------
__global__ void k_prep(const float* __restrict__ W1, const float* __restrict__ as1,
                       const float* __restrict__ ad1,
                       const float* __restrict__ W2, const float* __restrict__ as2,
                       const float* __restrict__ ad2,
                       const float* __restrict__ W3, const float* __restrict__ as3,
                       const float* __restrict__ ad3,
                       unsigned short* __restrict__ Wp2, unsigned short* __restrict__ Wp3,
                       float* __restrict__ M1f,
                       unsigned short* __restrict__ Mp2, unsigned short* __restrict__ Mp3){
    int id = blockIdx.x * 256 + threadIdx.x;
    if (id < 65536){
        int k = id >> 8, o = id & 255;
        int srccol = (o & 3) * 64 + (o >> 2);   // head (o&3), channel (o>>2)
        Wp2[(((k >> 3) * 256) + o) * 8 + (k & 7)] = f2bf(W2[k * 256 + srccol]);
    } else if (id < 81920){
        int i = id - 65536;
        int k = i >> 6, n = i & 63;
        Wp3[(((k >> 3) * 64) + n) * 8 + (k & 7)] = f2bf(W3[i]);
    } else if (id < 82048){
        int i = id - 81920;
        int k = i >> 3, j = i & 7;
        int h = j & 3;
        const float* a = (j < 4) ? as1 : ad1;
        float s = 0.f;
        for (int c = 0; c < 64; c++) s += W1[k * 256 + h * 64 + c] * a[h * 64 + c];
        M1f[k * 8 + j] = s;
    } else if (id < 86144){
        int i = id - 82048;
        int k = i >> 4, col = i & 15;
        float s = 0.f;
        if (col < 8){
            int h = col & 3;
            const float* a = (col < 4) ? as2 : ad2;
            for (int c = 0; c < 64; c++) s += W2[k * 256 + h * 64 + c] * a[h * 64 + c];
        }
        Mp2[((k >> 3) * 16 + col) * 8 + (k & 7)] = f2bf(s);
    } else if (id < 90240){
        int i = id - 86144;
        int k = i >> 4, col = i & 15;
        float s = 0.f;
        if (col < 2){
            const float* a = (col == 0) ? as3 : ad3;
            for (int c = 0; c < 64; c++) s += W3[k * 64 + c] * a[c];
        }
        Mp3[((k >> 3) * 16 + col) * 8 + (k & 7)] = f2bf(s);
    }
}

// ---------------- GraphNorm + conv1 GEMM + conv1 logits (one block/graph) ----
__global__ void __launch_bounds__(256)
k_gnorm_conv1(const float* __restrict__ x, const float* __restrict__ w,
              const float* __restrict__ b, const float* __restrict__ ms,
              const float* __restrict__ W1, const float* __restrict__ M1f,
              unsigned short* __restrict__ Ybf, float* __restrict__ lg1){
    __shared__ float sx[NPG * F_IN];
    __shared__ float Ws[16][256];
    __shared__ float red[16][16];
    __shared__ float meanS[16], varS[16];
    int g = blockIdx.x, t = threadIdx.x;
    int base = g * NPG;
    for (int idx = t; idx < NPG * F_IN; idx += 256) sx[idx] = x[base * F_IN + idx];
    for (int i = t; i < 1024; i += 256)
        *(float4*)&Ws[0][i * 4] = *(const float4*)&W1[i * 4];
    __syncthreads();
    int f = t & 15, grp = t >> 4;
    float p = 0.f;
    for (int i = grp; i < NPG; i += 16) p += sx[i * 16 + f];
    red[grp][f] = p; __syncthreads();
    if (t < 16){
        float s = 0.f;
        for (int i = 0; i < 16; i++) s += red[i][t];
        meanS[t] = s * (1.f / 100.f);
    }
    __syncthreads();
    float mm = meanS[f] * ms[f];
    p = 0.f;
    for (int i = grp; i < NPG; i += 16){ float v = sx[i * 16 + f] - mm; p += v * v; }
    red[grp][f] = p; __syncthreads();
    if (t < 16){
        float s = 0.f;
        for (int i = 0; i < 16; i++) s += red[i][t];
        varS[t] = s * (1.f / 100.f);
    }
    __syncthreads();
    for (int idx = t; idx < NPG * F_IN; idx += 256){
        int ff = idx & 15;
        sx[idx] = w[ff] * (sx[idx] - meanS[ff] * ms[ff]) * rsqrtf(varS[ff] + 1e-5f) + b[ff];
    }
    __syncthreads();
    int c4 = t & 15, rsub = t >> 4;
    for (int n = rsub; n < NPG; n += 16){
        float acc[16];   // [hh*4 + j]
        #pragma unroll
        for (int j = 0; j < 16; j++) acc[j] = 0.f;
        #pragma unroll
        for (int k = 0; k < 16; k++){
            float a_ = sx[n * 16 + k];
            float4 b0 = *(const float4*)&Ws[k][c4 * 4];
            float4 b1 = *(const float4*)&Ws[k][64 + c4 * 4];
            float4 b2 = *(const float4*)&Ws[k][128 + c4 * 4];
            float4 b3 = *(const float4*)&Ws[k][192 + c4 * 4];
            float bv[16] = {b0.x, b0.y, b0.z, b0.w, b1.x, b1.y, b1.z, b1.w,
                            b2.x, b2.y, b2.z, b2.w, b3.x, b3.y, b3.z, b3.w};
            #pragma unroll
            for (int j = 0; j < 16; j++) acc[j] = fmaf(a_, bv[j], acc[j]);
        }
        ushort8 ua, ub;
        #pragma unroll
        for (int m = 0; m < 8; m++){
            ua[m] = f2bf(acc[(m & 3) * 4 + (m >> 2)]);
            ub[m] = f2bf(acc[(m & 3) * 4 + 2 + (m >> 2)]);
        }
        size_t ob = (size_t)(base + n) * 256 + c4 * 16;
        *(ushort8*)&Ybf[ob]     = ua;
        *(ushort8*)&Ybf[ob + 8] = ub;
    }
    for (int i = t; i < NPG * 8; i += 256){
        int n = i >> 3, j = i & 7;
        float s = 0.f;
        #pragma unroll
        for (int ff = 0; ff < 16; ff++) s += sx[n * 16 + ff] * M1f[ff * 8 + j];
        lg1[(size_t)(base + n) * 8 + j] = s;
    }
}

// ---------------- fused GAT layer (H=4, conv1), one block (512 thr) per graph
__global__ void __launch_bounds__(512)
k_fused4(const unsigned short* __restrict__ hbf, const float* __restrict__ lg,
         const float* __restrict__ bias,
         const unsigned* __restrict__ csr, const int* __restrict__ noff,
         const int* __restrict__ cnt, unsigned short* __restrict__ out_bf){
    __shared__ __align__(16) unsigned int edl[EW_CAP][4];    // {w01,w23,sd,pad}
    __shared__ __align__(16) float asrcl[NPG * 4], adstl[NPG * 4];   // [n][h]
    __shared__ __align__(16) float wselfl[NPG * 4], rsuml[NPG * 4];  // [n][h]
    __shared__ int offl[NPG], cntl[NPG];

    int g = blockIdx.x, t = threadIdx.x;
    int wave = t >> 6, lane = t & 63;
    int base = g * NPG;
    size_t ebeg = (size_t)g * EW_CAP;

    if (t < NPG){
        offl[t] = noff[base + t];
        cntl[t] = cnt[base + t];
        const float* lp = lg + (size_t)(base + t) * 8;
        *(float4*)&asrcl[t * 4] = *(const float4*)lp;
        *(float4*)&adstl[t * 4] = *(const float4*)(lp + 4);
    }
    __syncthreads();
    int eln = offl[NPG - 1] + cntl[NPG - 1];
    for (int i = t; i < eln; i += 512) edl[i][2] = csr[ebeg + i];
    __syncthreads();

    for (int i = t; i < eln; i += 512){
        unsigned sd = edl[i][2];
        int s = sd & 0xFF, d = sd >> 8;
        float4 av = *(const float4*)&asrcl[s * 4];
        float4 dv = *(const float4*)&adstl[d * 4];
        unsigned w0 = f2bf(expf(lrelu(av.x + dv.x)));
        unsigned w1 = f2bf(expf(lrelu(av.y + dv.y)));
        unsigned w2 = f2bf(expf(lrelu(av.z + dv.z)));
        unsigned w3 = f2bf(expf(lrelu(av.w + dv.w)));
        edl[i][0] = w0 | (w1 << 16);
        edl[i][1] = w2 | (w3 << 16);
    }
    __syncthreads();

    if (t < NPG){
        int d = t;
        float4 av = *(const float4*)&asrcl[d * 4];
        float4 dv = *(const float4*)&adstl[d * 4];
        float ws0 = expf(lrelu(av.x + dv.x));
        float ws1 = expf(lrelu(av.y + dv.y));
        float ws2 = expf(lrelu(av.z + dv.z));
        float ws3 = expf(lrelu(av.w + dv.w));
        float s0 = ws0, s1 = ws1, s2 = ws2, s3 = ws3;
        int ebg = offl[d], n = cntl[d];
        for (int j = 0; j < n; j++){
            uint2 v = *(const uint2*)&edl[ebg + j][0];
            s0 += bf2f_lo(v.x); s1 += bf2f_hi(v.x);
            s2 += bf2f_lo(v.y); s3 += bf2f_hi(v.y);
        }
        *(float4*)&wselfl[d * 4] = make_float4(ws0, ws1, ws2, ws3);
        *(float4*)&rsuml[d * 4]  = make_float4(1.f / s0, 1.f / s1, 1.f / s2, 1.f / s3);
    }
    __syncthreads();

    float b0 = bias[lane], b1 = bias[64 + lane], b2 = bias[128 + lane], b3 = bias[192 + lane];
    for (int d = wave; d < NPG; d += 8){
        float4 ws = *(const float4*)&wselfl[d * 4];
        float4 rs = *(const float4*)&rsuml[d * 4];
        ushort4 hv = *(const ushort4*)&hbf[(size_t)(base + d) * 256 + lane * 4];
        float a0 = ws.x * bf2f(hv.x);
        float a1 = ws.y * bf2f(hv.y);
        float a2 = ws.z * bf2f(hv.z);
        float a3 = ws.w * bf2f(hv.w);
        int ebg = offl[d], n = cntl[d];
        int j = 0;
        #pragma unroll 1
        for (; j + 4 <= n; j += 4){
            #pragma unroll
            for (int k = 0; k < 4; k++){
                uint4 v = *(const uint4*)&edl[ebg + j + k][0];
                int s = (int)(v.z & 0xFFu);
                ushort4 x = *(const ushort4*)&hbf[(size_t)(base + s) * 256 + lane * 4];
                a0 = fmaf(bf2f_lo(v.x), bf2f(x.x), a0);
                a1 = fmaf(bf2f_hi(v.x), bf2f(x.y), a1);
                a2 = fmaf(bf2f_lo(v.y), bf2f(x.z), a2);
                a3 = fmaf(bf2f_hi(v.y), bf2f(x.w), a3);
            }
        }
        for (; j < n; j++){
            uint4 v = *(const uint4*)&edl[ebg + j][0];
            int s = (int)(v.z & 0xFFu);
            ushort4 x = *(const ushort4*)&hbf[(size_t)(base + s) * 256 + lane * 4];
            a0 = fmaf(bf2f_lo(v.x), bf2f(x.x), a0);
            a1 = fmaf(bf2f_hi(v.x), bf2f(x.y), a1);
            a2 = fmaf(bf2f_lo(v.y), bf2f(x.z), a2);
            a3 = fmaf(bf2f_hi(v.y), bf2f(x.w), a3);
        }
        size_t ob = (size_t)(base + d) * 256 + lane;
        out_bf[ob]       = f2bf(eluf(a0 * rs.x + b0));
        out_bf[ob + 64]  = f2bf(eluf(a1 * rs.y + b1));
        out_bf[ob + 128] = f2bf(eluf(a2 * rs.z + b2));
        out_bf[ob + 192] = f2bf(eluf(a3 * rs.w + b3));
    }
}

// ---------------- fused mid: conv2 MFMA GEMM + logits + GAT attention --------
// Column-ownership GEMM: each wave owns 2 of 16 output fragments; B-fragments
// preloaded ONCE into registers (64 VGPR), then 7 row-tiles of 16 MFMAs each.
// Wave 7 additionally computes the logit fragment (Mp2 loads stay in-loop).
// Edge staging after GEMM (all threads). Aggregation from LDS; ELU; bf16 out.
__global__ void __launch_bounds__(512)
k_mid(const unsigned short* __restrict__ xbin, const unsigned short* __restrict__ Wp2,
      const unsigned short* __restrict__ Mp2, const float* __restrict__ bias,
      const unsigned* __restrict__ csr, const int* __restrict__ noff,
      const int* __restrict__ cnt, unsigned short* __restrict__ out_bf){
    __shared__ __align__(16) unsigned short hl[NPG * 256];   // [n][c][h] 51200 B
    __shared__ __align__(16) unsigned int edw[EW_CAP][2];    // {w01,w23} 11264 B
    __shared__ unsigned short eds[EW_CAP];                   // sd 2816 B
    __shared__ __align__(16) float asrcl[NPG * 4], adstl[NPG * 4];
    __shared__ __align__(16) float wselfl[NPG * 4], rsuml[NPG * 4];
    __shared__ int offl[NPG], cntl[NPG];

    int g = blockIdx.x, t = threadIdx.x;
    int wave = t >> 6, lane = t & 63;
    int quad = lane >> 4, ln = lane & 15;
    int base = g * NPG;
    size_t ebeg = (size_t)g * EW_CAP;

    // preload owned B-fragments (cols f0, f1) for all 8 k-steps
    int f0 = wave * 2, f1 = wave * 2 + 1;
    short8 bw0[8], bw1[8];
    #pragma unroll
    for (int s = 0; s < 8; s++){
        int kc = 4 * s + quad;
        bw0[s] = *(const short8*)(Wp2 + ((size_t)kc * 256 + f0 * 16 + ln) * 8);
        bw1[s] = *(const short8*)(Wp2 + ((size_t)kc * 256 + f1 * 16 + ln) * 8);
    }

    // 7 row-tiles of 16 rows each
    for (int tile = 0; tile < 7; tile++){
        const unsigned short* aptr = xbin + (size_t)(base + tile * 16 + ln) * 256 + quad * 8;
        floatx4 acc0 = (floatx4){0.f, 0.f, 0.f, 0.f};
        floatx4 acc1 = (floatx4){0.f, 0.f, 0.f, 0.f};
        floatx4 accL = (floatx4){0.f, 0.f, 0.f, 0.f};
        #pragma unroll
        for (int s = 0; s < 8; s++){
            short8 a = *(const short8*)(aptr + s * 32);
            acc0 = __builtin_amdgcn_mfma_f32_16x16x32_bf16(a, bw0[s], acc0, 0, 0, 0);
            acc1 = __builtin_amdgcn_mfma_f32_16x16x32_bf16(a, bw1[s], acc1, 0, 0, 0);
            if (wave == 7){
                int kc = 4 * s + quad;
                short8 m = *(const short8*)(Mp2 + ((size_t)kc * 16 + ln) * 8);
                accL = __builtin_amdgcn_mfma_f32_16x16x32_bf16(a, m, accL, 0, 0, 0);
            }
        }
        int rowb = tile * 16 + quad * 4;
        #pragma unroll
        for (int rg = 0; rg < 4; rg++){
            int row = rowb + rg;
            if (row < NPG){
                hl[row * 256 + f0 * 16 + ln] = f2bf(acc0[rg]);
                hl[row * 256 + f1 * 16 + ln] = f2bf(acc1[rg]);
            }
        }
        if (wave == 7 && ln < 8){
            #pragma unroll
            for (int rg = 0; rg < 4; rg++){
                int row = rowb + rg;
                if (row < NPG){
                    if (ln < 4) asrcl[row * 4 + ln] = accL[rg];
                    else        adstl[row * 4 + (ln - 4)] = accL[rg];
                }
            }
        }
    }
    // stage offsets + edge slab (all threads)
    if (t < NPG){
        offl[t] = noff[base + t];
        cntl[t] = cnt[base + t];
    }
    int el = noff[base + NPG - 1] + cnt[base + NPG - 1];
    for (int i = t; i < el; i += 512) eds[i] = (unsigned short)csr[ebeg + i];
    __syncthreads();
    int eln = el;

    // edge-parallel softmax numerators (all 4 heads)
    for (int i = t; i < eln; i += 512){
        unsigned sd = eds[i];
        int s = sd & 0xFF, d = sd >> 8;
        float4 av = *(const float4*)&asrcl[s * 4];
        float4 dv = *(const float4*)&adstl[d * 4];
        unsigned w0 = f2bf(expf(lrelu(av.x + dv.x)));
        unsigned w1 = f2bf(expf(lrelu(av.y + dv.y)));
        unsigned w2 = f2bf(expf(lrelu(av.z + dv.z)));
        unsigned w3 = f2bf(expf(lrelu(av.w + dv.w)));
        edw[i][0] = w0 | (w1 << 16);
        edw[i][1] = w2 | (w3 << 16);
    }
    __syncthreads();

    // per-dst sums + self weight
    if (t < NPG){
        int d = t;
        float4 av = *(const float4*)&asrcl[d * 4];
        float4 dv = *(const float4*)&adstl[d * 4];
        float ws0 = expf(lrelu(av.x + dv.x));
        float ws1 = expf(lrelu(av.y + dv.y));
        float ws2 = expf(lrelu(av.z + dv.z));
        float ws3 = expf(lrelu(av.w + dv.w));
        float s0 = ws0, s1 = ws1, s2 = ws2, s3 = ws3;
        int ebg = offl[d], n = cntl[d];
        for (int j = 0; j < n; j++){
            uint2 v = *(const uint2*)&edw[ebg + j][0];
            s0 += bf2f_lo(v.x); s1 += bf2f_hi(v.x);
            s2 += bf2f_lo(v.y); s3 += bf2f_hi(v.y);
        }
        *(float4*)&wselfl[d * 4] = make_float4(ws0, ws1, ws2, ws3);
        *(float4*)&rsuml[d * 4]  = make_float4(1.f / s0, 1.f / s1, 1.f / s2, 1.f / s3);
    }
    __syncthreads();

    // aggregation from LDS, one wave per dst node, lane = channel
    float b0 = bias[lane], b1 = bias[64 + lane], b2 = bias[128 + lane], b3 = bias[192 + lane];
    for (int d = wave; d < NPG; d += 8){
        float4 ws = *(const float4*)&wselfl[d * 4];
        float4 rs = *(const float4*)&rsuml[d * 4];
        ushort4 hv = *(const ushort4*)&hl[d * 256 + lane * 4];
        float a0 = ws.x * bf2f(hv.x);
        float a1 = ws.y * bf2f(hv.y);
        float a2 = ws.z * bf2f(hv.z);
        float a3 = ws.w * bf2f(hv.w);
        int ebg = offl[d], n = cntl[d];
        int j = 0;
        #pragma unroll 1
        for (; j + 4 <= n; j += 4){
            #pragma unroll
            for (int k = 0; k < 4; k++){
                int s = (int)(eds[ebg + j + k] & 0xFFu);
                uint2 v = *(const uint2*)&edw[ebg + j + k][0];
                ushort4 x = *(const ushort4*)&hl[s * 256 + lane * 4];
                a0 = fmaf(bf2f_lo(v.x), bf2f(x.x), a0);
                a1 = fmaf(bf2f_hi(v.x), bf2f(x.y), a1);
                a2 = fmaf(bf2f_lo(v.y), bf2f(x.z), a2);
                a3 = fmaf(bf2f_hi(v.y), bf2f(x.w), a3);
            }
        }
        for (; j < n; j++){
            int s = (int)(eds[ebg + j] & 0xFFu);
            uint2 v = *(const uint2*)&edw[ebg + j][0];
            ushort4 x = *(const ushort4*)&hl[s * 256 + lane * 4];
            a0 = fmaf(bf2f_lo(v.x), bf2f(x.x), a0);
            a1 = fmaf(bf2f_hi(v.x), bf2f(x.y), a1);
            a2 = fmaf(bf2f_lo(v.y), bf2f(x.z), a2);
            a3 = fmaf(bf2f_hi(v.y), bf2f(x.w), a3);
        }
        size_t ob = (size_t)(base + d) * 256 + lane;
        out_bf[ob]       = f2bf(eluf(a0 * rs.x + b0));
        out_bf[ob + 64]  = f2bf(eluf(a1 * rs.y + b1));
        out_bf[ob + 128] = f2bf(eluf(a2 * rs.z + b2));
        out_bf[ob + 192] = f2bf(eluf(a3 * rs.w + b3));
    }
}

// ---------------- fused tail: conv3 MFMA GEMM + logits + GAT agg + pool + head
__global__ void __launch_bounds__(512)
k_tail(const unsigned short* __restrict__ xb, const unsigned short* __restrict__ Wp3,
       const unsigned short* __restrict__ Mp3, const float* __restrict__ bias,
       const unsigned* __restrict__ csr, const int* __restrict__ noff,
       const int* __restrict__ cnt, const float* __restrict__ gin,
       const float* __restrict__ bn_g, const float* __restrict__ bn_b,
       const float* __restrict__ bn_m, const float* __restrict__ bn_v,
       const float* __restrict__ Wd1, const float* __restrict__ bd1,
       const float* __restrict__ Wd2, const float* __restrict__ bd2,
       const float* __restrict__ Wo, const float* __restrict__ bo,
       float* __restrict__ out){
    __shared__ __align__(16) unsigned short h3[NPG * 64];   // [n][c] bf16, 12.8 KB
    __shared__ __align__(16) unsigned int edl[EW_CAP][2];   // {w, sd} 11.3 KB
    __shared__ float asrcl[NPG], adstl[NPG];
    __shared__ float wselfl[NPG], rsuml[NPG];
    __shared__ int offl[NPG], cntl[NPG];
    __shared__ float red[8][64];
    __shared__ float gv[68], g2[64], g3[64];

    int g = blockIdx.x, t = threadIdx.x;
    int wave = t >> 6, lane = t & 63;
    int base = g * NPG;
    size_t ebeg = (size_t)g * EW_CAP;

    if (wave < 7){
        int quad = lane >> 4, ln = lane & 15;
        floatx4 acc[4];
        #pragma unroll
        for (int f = 0; f < 4; f++) acc[f] = (floatx4){0.f, 0.f, 0.f, 0.f};
        floatx4 accL = (floatx4){0.f, 0.f, 0.f, 0.f};
        const unsigned short* aptr = xb + (size_t)(base + wave * 16 + ln) * 256 + quad * 8;
        for (int kt = 0; kt < 256; kt += 32){
            short8 a = *(const short8*)(aptr + kt);
            int kc = (kt >> 3) + quad;
            #pragma unroll
            for (int f = 0; f < 4; f++){
                short8 bfr = *(const short8*)(Wp3 + ((size_t)kc * 64 + f * 16 + ln) * 8);
                acc[f] = __builtin_amdgcn_mfma_f32_16x16x32_bf16(a, bfr, acc[f], 0, 0, 0);
            }
            short8 m = *(const short8*)(Mp3 + ((size_t)kc * 16 + ln) * 8);
            accL = __builtin_amdgcn_mfma_f32_16x16x32_bf16(a, m, accL, 0, 0, 0);
        }
        int rowb = wave * 16 + quad * 4;
        #pragma unroll
        for (int f = 0; f < 4; f++){
            int col = f * 16 + ln;
            #pragma unroll
            for (int rg = 0; rg < 4; rg++){
                int row = rowb + rg;
                if (row < NPG) h3[row * 64 + col] = f2bf(acc[f][rg]);
            }
        }
        if (ln < 2){
            #pragma unroll
            for (int rg = 0; rg < 4; rg++){
                int row = rowb + rg;
                if (row < NPG){
                    if (ln == 0) asrcl[row] = accL[rg];
                    else         adstl[row] = accL[rg];
                }
            }
        }
    } else {
        for (int i = lane; i < NPG; i += 64){
            offl[i] = noff[base + i];
            cntl[i] = cnt[base + i];
        }
        int el = noff[base + NPG - 1] + cnt[base + NPG - 1];
        for (int i = lane; i < el; i += 64) edl[i][1] = csr[ebeg + i];
    }
    __syncthreads();
    int eln = offl[NPG - 1] + cntl[NPG - 1];

    for (int i = t; i < eln; i += 512){
        unsigned sd = edl[i][1];
        int s = sd & 0xFF, d = sd >> 8;
        edl[i][0] = (unsigned)f2bf(expf(lrelu(asrcl[s] + adstl[d])));
    }
    __syncthreads();

    if (t < NPG){
        float wsf = expf(lrelu(asrcl[t] + adstl[t]));
        float sum = wsf;
        int ebg = offl[t], n = cntl[t];
        for (int j = 0; j < n; j++) sum += bf2f((unsigned short)edl[ebg + j][0]);
        wselfl[t] = wsf;
        rsuml[t] = 1.f / sum;
    }
    __syncthreads();

    float bl = bias[lane];
    float pool = 0.f;
    for (int d = wave; d < NPG; d += 8){
        float acc = wselfl[d] * bf2f(h3[d * 64 + lane]);
        int ebg = offl[d], n = cntl[d];
        for (int j = 0; j < n; j++){
            uint2 v = *(const uint2*)&edl[ebg + j][0];
            acc = fmaf(bf2f_lo(v.x), bf2f(h3[(int)(v.y & 0xFFu) * 64 + lane]), acc);
        }
        pool += acc * rsuml[d] + bl;
    }
    red[wave][lane] = pool;
    __syncthreads();

    if (t < 64){
        float s = 0.f;
        #pragma unroll
        for (int i = 0; i < 8; i++) s += red[i][t];
        float mean = s * (1.f / 100.f);
        gv[t] = (mean - bn_m[t]) * rsqrtf(bn_v[t] + 1e-5f) * bn_g[t] + bn_b[t];
    } else if (t < 68){
        int j = t - 64;
        float v = gin[g * 4 + j];
        gv[t] = (v - bn_m[t]) * rsqrtf(bn_v[t] + 1e-5f) * bn_g[t] + bn_b[t];
    }
    __syncthreads();
    if (t < 64){
        float s = bd1[t];
        for (int i = 0; i < 68; i++) s += gv[i] * Wd1[i * 64 + t];
        g2[t] = seluf(s);
    }
    __syncthreads();
    if (t < 64){
        float s = bd2[t];
        for (int i = 0; i < 64; i++) s += g2[i] * Wd2[i * 64 + t];
        g3[t] = seluf(s);
    }
    __syncthreads();
    if (t == 0){
        float l0 = bo[0], l1 = bo[1];
        for (int i = 0; i < 64; i++){ l0 += g3[i] * Wo[i * 2]; l1 += g3[i] * Wo[i * 2 + 1]; }
        float mx = fmaxf(l0, l1);
        float e0 = expf(l0 - mx), e1 = expf(l1 - mx);
        float inv = 1.f / (e0 + e1);
        out[g * 2] = e0 * inv;
        out[g * 2 + 1] = e1 * inv;
    }
}

extern "C" void kernel_launch(void* const* d_in, const int* in_sizes, int n_in,
                              void* d_out, int out_size, void* d_ws, size_t ws_size,
                              hipStream_t stream){
    const float* x   = (const float*)d_in[0];
    const int*   ei  = (const int*)d_in[1];
    const float* gin = (const float*)d_in[2];
    const float* gn_w = (const float*)d_in[4];
    const float* gn_b = (const float*)d_in[5];
    const float* gn_ms = (const float*)d_in[6];
    const float* W1 = (const float*)d_in[7];
    const float* as1 = (const float*)d_in[8];
    const float* ad1 = (const float*)d_in[9];
    const float* b1 = (const float*)d_in[10];
    const float* W2 = (const float*)d_in[11];
    const float* as2 = (const float*)d_in[12];
    const float* ad2 = (const float*)d_in[13];
    const float* b2 = (const float*)d_in[14];
    const float* W3 = (const float*)d_in[15];
    const float* as3 = (const float*)d_in[16];
    const float* ad3 = (const float*)d_in[17];
    const float* b3 = (const float*)d_in[18];
    const float* bn_g = (const float*)d_in[19];
    const float* bn_b = (const float*)d_in[20];
    const float* bn_m = (const float*)d_in[21];
    const float* bn_v = (const float*)d_in[22];
    const float* Wd1 = (const float*)d_in[23];
    const float* bd1 = (const float*)d_in[24];
    const float* Wd2 = (const float*)d_in[25];
    const float* bd2 = (const float*)d_in[26];
    const float* Wo = (const float*)d_in[27];
    const float* bo = (const float*)d_in[28];
    float* out = (float*)d_out;

    const int* src = ei;
    const int* dst = ei + N_EDGES;

    char* ws = (char*)d_ws;
    size_t off = 0;
    auto alloc = [&](size_t bytes) -> void* {
        void* p = ws + off;
        off = (off + bytes + 255) & ~(size_t)255;
        return p;
    };
    int* counts     = (int*)alloc((size_t)N_NODES * 4);
    int* write_ptr  = (int*)alloc((size_t)N_NODES * 4);
    unsigned* csr   = (unsigned*)alloc((size_t)N_GRAPHS * EW_CAP * 4);
    int* noff       = (int*)alloc((size_t)N_NODES * 4);
    int* cnt        = (int*)alloc((size_t)N_NODES * 4);
    unsigned short* wp2 = (unsigned short*)alloc((size_t)256 * 256 * 2);
    unsigned short* wp3 = (unsigned short*)alloc((size_t)256 * 64 * 2);
    float* M1f      = (float*)alloc((size_t)16 * 8 * 4);
    unsigned short* Mp2 = (unsigned short*)alloc((size_t)32 * 16 * 8 * 2);
    unsigned short* Mp3 = (unsigned short*)alloc((size_t)32 * 16 * 8 * 2);
    float* lg1      = (float*)alloc((size_t)N_NODES * 8 * 4);
    unsigned short* xbh = (unsigned short*)alloc((size_t)N_ROWS_PAD * 256 * 2); // conv1 GEMM out (interleaved) / k_mid attention out (row-major)
    unsigned short* xb  = (unsigned short*)alloc((size_t)N_ROWS_PAD * 256 * 2); // fused4-conv1 out (row-major, k_mid GEMM A input)

    // --- CSR build (slab format, graph-local offsets; no global scan) ---
    hipMemsetAsync(counts, 0, (size_t)N_NODES * 4, stream);
    k_count<<<(N_EDGES + 255) / 256, 256, 0, stream>>>(dst, counts);
    k_prep<<<(90240 + 255) / 256, 256, 0, stream>>>(W1, as1, ad1, W2, as2, ad2,
                                                    W3, as3, ad3, wp2, wp3, M1f, Mp2, Mp3);
    k_local_scan<<<N_GRAPHS, 128, 0, stream>>>(counts, noff, cnt, write_ptr);
    k_scatter<<<(N_EDGES + 255) / 256, 256, 0, stream>>>(src, dst, write_ptr, csr);

    // --- GraphNorm + conv1 GEMM + conv1 logits (fused, one block/graph) ---
    k_gnorm_conv1<<<N_GRAPHS, 256, 0, stream>>>(x, gn_w, gn_b, gn_ms, W1, M1f, xbh, lg1);
    k_fused4<<<N_GRAPHS, 512, 0, stream>>>(xbh, lg1, b1, csr, noff, cnt, xb);

    // --- conv2 GEMM + logits + attention (fused, one block/graph) ---
    k_mid<<<N_GRAPHS, 512, 0, stream>>>(xb, wp2, Mp2, b2, csr, noff, cnt, xbh);

    // --- conv3 + GAT agg + pool + BN + dense head + softmax (one block/graph) ---
    k_tail<<<N_GRAPHS, 512, 0, stream>>>(xbh, wp3, Mp3, b3, csr, noff, cnt, gin,
                                         bn_g, bn_b, bn_m, bn_v,
                                         Wd1, bd1, Wd2, bd2, Wo, bo, out);
}

// Round 14
// 307.501 us; speedup vs baseline: 1.0279x; 1.0279x over previous
//
#include <hip/hip_runtime.h>
#include <math.h>

#define N_NODES 50000
#define N_ROWS_PAD 50048   // 782 * 64
#define N_GRAPHS 500
#define NPG 100
#define N_EDGES 500000
#define F_IN 16
#define HID 64
#define EW_CAP 1408        // max intra-graph edges (mean 1000, sigma ~32 -> +12.9 sigma)

#define SELU_SCALE 1.0507009873554804934193349852946f
#define SELU_ALPHA 1.6732632423543772848170429916717f

typedef __attribute__((ext_vector_type(8))) short short8;
typedef __attribute__((ext_vector_type(8))) unsigned short ushort8;
typedef __attribute__((ext_vector_type(4))) float floatx4;

__device__ __forceinline__ float lrelu(float x){ return x > 0.f ? x : 0.2f * x; }
__device__ __forceinline__ float eluf(float x){ return x > 0.f ? x : expf(x) - 1.f; }
__device__ __forceinline__ float seluf(float x){
    return x > 0.f ? SELU_SCALE * x : SELU_SCALE * (SELU_ALPHA * (expf(x) - 1.f));
}
__device__ __forceinline__ unsigned short f2bf(float x){
    unsigned u = __float_as_uint(x);
    return (unsigned short)((u + 0x7FFFu + ((u >> 16) & 1u)) >> 16);
}
__device__ __forceinline__ float bf2f(unsigned short u){
    return __uint_as_float((unsigned)u << 16);
}
__device__ __forceinline__ float bf2f_lo(unsigned u){
    return __uint_as_float(u << 16);
}
__device__ __forceinline__ float bf2f_hi(unsigned u){
    return __uint_as_float(u & 0xFFFF0000u);
}

// ---------------- CSR build (slab format, graph-local offsets) ----------------
__global__ void k_count(const int* __restrict__ dst, int* __restrict__ counts){
    int e = blockIdx.x * 256 + threadIdx.x;
    if (e < N_EDGES) atomicAdd(&counts[dst[e]], 1);
}

__global__ void __launch_bounds__(128)
k_local_scan(const int* __restrict__ counts, int* __restrict__ noff,
             int* __restrict__ cnt, int* __restrict__ write_ptr){
    __shared__ int s[128];
    int g = blockIdx.x, t = threadIdx.x;
    int v = (t < NPG) ? counts[g * NPG + t] : 0;
    s[t] = v; __syncthreads();
    for (int o = 1; o < 128; o <<= 1){
        int x = (t >= o) ? s[t - o] : 0;
        __syncthreads();
        s[t] += x;
        __syncthreads();
    }
    if (t < NPG){
        int excl = s[t] - v;
        noff[g * NPG + t] = excl;     // graph-local exclusive offset
        cnt[g * NPG + t] = v;
        write_ptr[g * NPG + t] = excl;
    }
}

__global__ void k_scatter(const int* __restrict__ src, const int* __restrict__ dst,
                          int* __restrict__ write_ptr, unsigned* __restrict__ csr){
    int e = blockIdx.x * 256 + threadIdx.x;
    if (e < N_EDGES){
        int d = dst[e];
        int g = d / NPG;
        int b = g * NPG;
        int pos = atomicAdd(&write_ptr[d], 1);
        csr[(size_t)g * EW_CAP + pos] = (unsigned)((src[e] - b) | ((d - b) << 8));
    }
}

// ---------------- prep: weight packs + logit matrices ----------------
__global__ void k_prep(const float* __restrict__ W1, const float* __restrict__ as1,
                       const float* __restrict__ ad1,
                       const float* __restrict__ W2, const float* __restrict__ as2,
                       const float* __restrict__ ad2,
                       const float* __restrict__ W3, const float* __restrict__ as3,
                       const float* __restrict__ ad3,
                       unsigned short* __restrict__ Wp2, unsigned short* __restrict__ Wp3,
                       float* __restrict__ M1f,
                       unsigned short* __restrict__ Mp2, unsigned short* __restrict__ Mp3){
    int id = blockIdx.x * 256 + threadIdx.x;
    if (id < 65536){
        int k = id >> 8, o = id & 255;
        int srccol = (o & 3) * 64 + (o >> 2);   // head (o&3), channel (o>>2)
        Wp2[(((k >> 3) * 256) + o) * 8 + (k & 7)] = f2bf(W2[k * 256 + srccol]);
    } else if (id < 81920){
        int i = id - 65536;
        int k = i >> 6, n = i & 63;
        Wp3[(((k >> 3) * 64) + n) * 8 + (k & 7)] = f2bf(W3[i]);
    } else if (id < 82048){
        int i = id - 81920;
        int k = i >> 3, j = i & 7;
        int h = j & 3;
        const float* a = (j < 4) ? as1 : ad1;
        float s = 0.f;
        for (int c = 0; c < 64; c++) s += W1[k * 256 + h * 64 + c] * a[h * 64 + c];
        M1f[k * 8 + j] = s;
    } else if (id < 86144){
        int i = id - 82048;
        int k = i >> 4, col = i & 15;
        float s = 0.f;
        if (col < 8){
            int h = col & 3;
            const float* a = (col < 4) ? as2 : ad2;
            for (int c = 0; c < 64; c++) s += W2[k * 256 + h * 64 + c] * a[h * 64 + c];
        }
        Mp2[((k >> 3) * 16 + col) * 8 + (k & 7)] = f2bf(s);
    } else if (id < 90240){
        int i = id - 86144;
        int k = i >> 4, col = i & 15;
        float s = 0.f;
        if (col < 2){
            const float* a = (col == 0) ? as3 : ad3;
            for (int c = 0; c < 64; c++) s += W3[k * 64 + c] * a[c];
        }
        Mp3[((k >> 3) * 16 + col) * 8 + (k & 7)] = f2bf(s);
    }
}

// ---------------- GraphNorm + conv1 GEMM + conv1 logits (one block/graph) ----
__global__ void __launch_bounds__(256)
k_gnorm_conv1(const float* __restrict__ x, const float* __restrict__ w,
              const float* __restrict__ b, const float* __restrict__ ms,
              const float* __restrict__ W1, const float* __restrict__ M1f,
              unsigned short* __restrict__ Ybf, float* __restrict__ lg1){
    __shared__ float sx[NPG * F_IN];
    __shared__ float Ws[16][256];
    __shared__ float red[16][16];
    __shared__ float meanS[16], varS[16];
    int g = blockIdx.x, t = threadIdx.x;
    int base = g * NPG;
    for (int idx = t; idx < NPG * F_IN; idx += 256) sx[idx] = x[base * F_IN + idx];
    for (int i = t; i < 1024; i += 256)
        *(float4*)&Ws[0][i * 4] = *(const float4*)&W1[i * 4];
    __syncthreads();
    int f = t & 15, grp = t >> 4;
    float p = 0.f;
    for (int i = grp; i < NPG; i += 16) p += sx[i * 16 + f];
    red[grp][f] = p; __syncthreads();
    if (t < 16){
        float s = 0.f;
        for (int i = 0; i < 16; i++) s += red[i][t];
        meanS[t] = s * (1.f / 100.f);
    }
    __syncthreads();
    float mm = meanS[f] * ms[f];
    p = 0.f;
    for (int i = grp; i < NPG; i += 16){ float v = sx[i * 16 + f] - mm; p += v * v; }
    red[grp][f] = p; __syncthreads();
    if (t < 16){
        float s = 0.f;
        for (int i = 0; i < 16; i++) s += red[i][t];
        varS[t] = s * (1.f / 100.f);
    }
    __syncthreads();
    for (int idx = t; idx < NPG * F_IN; idx += 256){
        int ff = idx & 15;
        sx[idx] = w[ff] * (sx[idx] - meanS[ff] * ms[ff]) * rsqrtf(varS[ff] + 1e-5f) + b[ff];
    }
    __syncthreads();
    int c4 = t & 15, rsub = t >> 4;
    for (int n = rsub; n < NPG; n += 16){
        float acc[16];   // [hh*4 + j]
        #pragma unroll
        for (int j = 0; j < 16; j++) acc[j] = 0.f;
        #pragma unroll
        for (int k = 0; k < 16; k++){
            float a_ = sx[n * 16 + k];
            float4 b0 = *(const float4*)&Ws[k][c4 * 4];
            float4 b1 = *(const float4*)&Ws[k][64 + c4 * 4];
            float4 b2 = *(const float4*)&Ws[k][128 + c4 * 4];
            float4 b3 = *(const float4*)&Ws[k][192 + c4 * 4];
            float bv[16] = {b0.x, b0.y, b0.z, b0.w, b1.x, b1.y, b1.z, b1.w,
                            b2.x, b2.y, b2.z, b2.w, b3.x, b3.y, b3.z, b3.w};
            #pragma unroll
            for (int j = 0; j < 16; j++) acc[j] = fmaf(a_, bv[j], acc[j]);
        }
        ushort8 ua, ub;
        #pragma unroll
        for (int m = 0; m < 8; m++){
            ua[m] = f2bf(acc[(m & 3) * 4 + (m >> 2)]);
            ub[m] = f2bf(acc[(m & 3) * 4 + 2 + (m >> 2)]);
        }
        size_t ob = (size_t)(base + n) * 256 + c4 * 16;
        *(ushort8*)&Ybf[ob]     = ua;
        *(ushort8*)&Ybf[ob + 8] = ub;
    }
    for (int i = t; i < NPG * 8; i += 256){
        int n = i >> 3, j = i & 7;
        float s = 0.f;
        #pragma unroll
        for (int ff = 0; ff < 16; ff++) s += sx[n * 16 + ff] * M1f[ff * 8 + j];
        lg1[(size_t)(base + n) * 8 + j] = s;
    }
}

// ---------------- fused GAT layer (H=4, conv1), one block (512 thr) per graph
__global__ void __launch_bounds__(512)
k_fused4(const unsigned short* __restrict__ hbf, const float* __restrict__ lg,
         const float* __restrict__ bias,
         const unsigned* __restrict__ csr, const int* __restrict__ noff,
         const int* __restrict__ cnt, unsigned short* __restrict__ out_bf){
    __shared__ __align__(16) unsigned int edl[EW_CAP][4];    // {w01,w23,sd,pad}
    __shared__ __align__(16) float asrcl[NPG * 4], adstl[NPG * 4];   // [n][h]
    __shared__ __align__(16) float wselfl[NPG * 4], rsuml[NPG * 4];  // [n][h]
    __shared__ int offl[NPG], cntl[NPG];

    int g = blockIdx.x, t = threadIdx.x;
    int wave = t >> 6, lane = t & 63;
    int base = g * NPG;
    size_t ebeg = (size_t)g * EW_CAP;

    if (t < NPG){
        offl[t] = noff[base + t];
        cntl[t] = cnt[base + t];
        const float* lp = lg + (size_t)(base + t) * 8;
        *(float4*)&asrcl[t * 4] = *(const float4*)lp;
        *(float4*)&adstl[t * 4] = *(const float4*)(lp + 4);
    }
    __syncthreads();
    int eln = offl[NPG - 1] + cntl[NPG - 1];
    for (int i = t; i < eln; i += 512) edl[i][2] = csr[ebeg + i];
    __syncthreads();

    for (int i = t; i < eln; i += 512){
        unsigned sd = edl[i][2];
        int s = sd & 0xFF, d = sd >> 8;
        float4 av = *(const float4*)&asrcl[s * 4];
        float4 dv = *(const float4*)&adstl[d * 4];
        unsigned w0 = f2bf(expf(lrelu(av.x + dv.x)));
        unsigned w1 = f2bf(expf(lrelu(av.y + dv.y)));
        unsigned w2 = f2bf(expf(lrelu(av.z + dv.z)));
        unsigned w3 = f2bf(expf(lrelu(av.w + dv.w)));
        edl[i][0] = w0 | (w1 << 16);
        edl[i][1] = w2 | (w3 << 16);
    }
    __syncthreads();

    if (t < NPG){
        int d = t;
        float4 av = *(const float4*)&asrcl[d * 4];
        float4 dv = *(const float4*)&adstl[d * 4];
        float ws0 = expf(lrelu(av.x + dv.x));
        float ws1 = expf(lrelu(av.y + dv.y));
        float ws2 = expf(lrelu(av.z + dv.z));
        float ws3 = expf(lrelu(av.w + dv.w));
        float s0 = ws0, s1 = ws1, s2 = ws2, s3 = ws3;
        int ebg = offl[d], n = cntl[d];
        for (int j = 0; j < n; j++){
            uint2 v = *(const uint2*)&edl[ebg + j][0];
            s0 += bf2f_lo(v.x); s1 += bf2f_hi(v.x);
            s2 += bf2f_lo(v.y); s3 += bf2f_hi(v.y);
        }
        *(float4*)&wselfl[d * 4] = make_float4(ws0, ws1, ws2, ws3);
        *(float4*)&rsuml[d * 4]  = make_float4(1.f / s0, 1.f / s1, 1.f / s2, 1.f / s3);
    }
    __syncthreads();

    float b0 = bias[lane], b1 = bias[64 + lane], b2 = bias[128 + lane], b3 = bias[192 + lane];
    for (int d = wave; d < NPG; d += 8){
        float4 ws = *(const float4*)&wselfl[d * 4];
        float4 rs = *(const float4*)&rsuml[d * 4];
        ushort4 hv = *(const ushort4*)&hbf[(size_t)(base + d) * 256 + lane * 4];
        float a0 = ws.x * bf2f(hv.x);
        float a1 = ws.y * bf2f(hv.y);
        float a2 = ws.z * bf2f(hv.z);
        float a3 = ws.w * bf2f(hv.w);
        int ebg = offl[d], n = cntl[d];
        int j = 0;
        #pragma unroll 1
        for (; j + 4 <= n; j += 4){
            #pragma unroll
            for (int k = 0; k < 4; k++){
                uint4 v = *(const uint4*)&edl[ebg + j + k][0];
                int s = (int)(v.z & 0xFFu);
                ushort4 x = *(const ushort4*)&hbf[(size_t)(base + s) * 256 + lane * 4];
                a0 = fmaf(bf2f_lo(v.x), bf2f(x.x), a0);
                a1 = fmaf(bf2f_hi(v.x), bf2f(x.y), a1);
                a2 = fmaf(bf2f_lo(v.y), bf2f(x.z), a2);
                a3 = fmaf(bf2f_hi(v.y), bf2f(x.w), a3);
            }
        }
        for (; j < n; j++){
            uint4 v = *(const uint4*)&edl[ebg + j][0];
            int s = (int)(v.z & 0xFFu);
            ushort4 x = *(const ushort4*)&hbf[(size_t)(base + s) * 256 + lane * 4];
            a0 = fmaf(bf2f_lo(v.x), bf2f(x.x), a0);
            a1 = fmaf(bf2f_hi(v.x), bf2f(x.y), a1);
            a2 = fmaf(bf2f_lo(v.y), bf2f(x.z), a2);
            a3 = fmaf(bf2f_hi(v.y), bf2f(x.w), a3);
        }
        size_t ob = (size_t)(base + d) * 256 + lane;
        out_bf[ob]       = f2bf(eluf(a0 * rs.x + b0));
        out_bf[ob + 64]  = f2bf(eluf(a1 * rs.y + b1));
        out_bf[ob + 128] = f2bf(eluf(a2 * rs.z + b2));
        out_bf[ob + 192] = f2bf(eluf(a3 * rs.w + b3));
    }
}

// ---------------- fused mid: conv2 MFMA GEMM + logits + GAT attention --------
// R12-proven structure: waves 0-6 each own one 16-row tile (17 independent
// accumulator chains per wave = full MFMA ILP); wave 7 stages the edge slab.
__global__ void __launch_bounds__(512)
k_mid(const unsigned short* __restrict__ xbin, const unsigned short* __restrict__ Wp2,
      const unsigned short* __restrict__ Mp2, const float* __restrict__ bias,
      const unsigned* __restrict__ csr, const int* __restrict__ noff,
      const int* __restrict__ cnt, unsigned short* __restrict__ out_bf){
    __shared__ __align__(16) unsigned short hl[NPG * 256];   // [n][c][h] 51200 B
    __shared__ __align__(16) unsigned int edw[EW_CAP][2];    // {w01,w23} 11264 B
    __shared__ unsigned short eds[EW_CAP];                   // sd 2816 B
    __shared__ __align__(16) float asrcl[NPG * 4], adstl[NPG * 4];
    __shared__ __align__(16) float wselfl[NPG * 4], rsuml[NPG * 4];
    __shared__ int offl[NPG], cntl[NPG];

    int g = blockIdx.x, t = threadIdx.x;
    int wave = t >> 6, lane = t & 63;
    int base = g * NPG;
    size_t ebeg = (size_t)g * EW_CAP;

    if (wave < 7){
        int quad = lane >> 4, ln = lane & 15;
        floatx4 acc[16];
        #pragma unroll
        for (int f = 0; f < 16; f++) acc[f] = (floatx4){0.f, 0.f, 0.f, 0.f};
        floatx4 accL = (floatx4){0.f, 0.f, 0.f, 0.f};
        const unsigned short* aptr = xbin + (size_t)(base + wave * 16 + ln) * 256 + quad * 8;
        for (int kt = 0; kt < 256; kt += 32){
            short8 a = *(const short8*)(aptr + kt);
            int kc = (kt >> 3) + quad;
            #pragma unroll
            for (int f = 0; f < 16; f++){
                short8 bfr = *(const short8*)(Wp2 + ((size_t)kc * 256 + f * 16 + ln) * 8);
                acc[f] = __builtin_amdgcn_mfma_f32_16x16x32_bf16(a, bfr, acc[f], 0, 0, 0);
            }
            short8 m = *(const short8*)(Mp2 + ((size_t)kc * 16 + ln) * 8);
            accL = __builtin_amdgcn_mfma_f32_16x16x32_bf16(a, m, accL, 0, 0, 0);
        }
        int rowb = wave * 16 + quad * 4;
        #pragma unroll
        for (int f = 0; f < 16; f++){
            int col = f * 16 + ln;
            #pragma unroll
            for (int rg = 0; rg < 4; rg++){
                int row = rowb + rg;
                if (row < NPG) hl[row * 256 + col] = f2bf(acc[f][rg]);
            }
        }
        if (ln < 8){
            #pragma unroll
            for (int rg = 0; rg < 4; rg++){
                int row = rowb + rg;
                if (row < NPG){
                    if (ln < 4) asrcl[row * 4 + ln] = accL[rg];
                    else        adstl[row * 4 + (ln - 4)] = accL[rg];
                }
            }
        }
    } else {
        for (int i = lane; i < NPG; i += 64){
            offl[i] = noff[base + i];
            cntl[i] = cnt[base + i];
        }
        int el = noff[base + NPG - 1] + cnt[base + NPG - 1];
        for (int i = lane; i < el; i += 64) eds[i] = (unsigned short)csr[ebeg + i];
    }
    __syncthreads();
    int eln = offl[NPG - 1] + cntl[NPG - 1];

    for (int i = t; i < eln; i += 512){
        unsigned sd = eds[i];
        int s = sd & 0xFF, d = sd >> 8;
        float4 av = *(const float4*)&asrcl[s * 4];
        float4 dv = *(const float4*)&adstl[d * 4];
        unsigned w0 = f2bf(expf(lrelu(av.x + dv.x)));
        unsigned w1 = f2bf(expf(lrelu(av.y + dv.y)));
        unsigned w2 = f2bf(expf(lrelu(av.z + dv.z)));
        unsigned w3 = f2bf(expf(lrelu(av.w + dv.w)));
        edw[i][0] = w0 | (w1 << 16);
        edw[i][1] = w2 | (w3 << 16);
    }
    __syncthreads();

    if (t < NPG){
        int d = t;
        float4 av = *(const float4*)&asrcl[d * 4];
        float4 dv = *(const float4*)&adstl[d * 4];
        float ws0 = expf(lrelu(av.x + dv.x));
        float ws1 = expf(lrelu(av.y + dv.y));
        float ws2 = expf(lrelu(av.z + dv.z));
        float ws3 = expf(lrelu(av.w + dv.w));
        float s0 = ws0, s1 = ws1, s2 = ws2, s3 = ws3;
        int ebg = offl[d], n = cntl[d];
        for (int j = 0; j < n; j++){
            uint2 v = *(const uint2*)&edw[ebg + j][0];
            s0 += bf2f_lo(v.x); s1 += bf2f_hi(v.x);
            s2 += bf2f_lo(v.y); s3 += bf2f_hi(v.y);
        }
        *(float4*)&wselfl[d * 4] = make_float4(ws0, ws1, ws2, ws3);
        *(float4*)&rsuml[d * 4]  = make_float4(1.f / s0, 1.f / s1, 1.f / s2, 1.f / s3);
    }
    __syncthreads();

    float b0 = bias[lane], b1 = bias[64 + lane], b2 = bias[128 + lane], b3 = bias[192 + lane];
    for (int d = wave; d < NPG; d += 8){
        float4 ws = *(const float4*)&wselfl[d * 4];
        float4 rs = *(const float4*)&rsuml[d * 4];
        ushort4 hv = *(const ushort4*)&hl[d * 256 + lane * 4];
        float a0 = ws.x * bf2f(hv.x);
        float a1 = ws.y * bf2f(hv.y);
        float a2 = ws.z * bf2f(hv.z);
        float a3 = ws.w * bf2f(hv.w);
        int ebg = offl[d], n = cntl[d];
        int j = 0;
        #pragma unroll 1
        for (; j + 4 <= n; j += 4){
            #pragma unroll
            for (int k = 0; k < 4; k++){
                int s = (int)(eds[ebg + j + k] & 0xFFu);
                uint2 v = *(const uint2*)&edw[ebg + j + k][0];
                ushort4 x = *(const ushort4*)&hl[s * 256 + lane * 4];
                a0 = fmaf(bf2f_lo(v.x), bf2f(x.x), a0);
                a1 = fmaf(bf2f_hi(v.x), bf2f(x.y), a1);
                a2 = fmaf(bf2f_lo(v.y), bf2f(x.z), a2);
                a3 = fmaf(bf2f_hi(v.y), bf2f(x.w), a3);
            }
        }
        for (; j < n; j++){
            int s = (int)(eds[ebg + j] & 0xFFu);
            uint2 v = *(const uint2*)&edw[ebg + j][0];
            ushort4 x = *(const ushort4*)&hl[s * 256 + lane * 4];
            a0 = fmaf(bf2f_lo(v.x), bf2f(x.x), a0);
            a1 = fmaf(bf2f_hi(v.x), bf2f(x.y), a1);
            a2 = fmaf(bf2f_lo(v.y), bf2f(x.z), a2);
            a3 = fmaf(bf2f_hi(v.y), bf2f(x.w), a3);
        }
        size_t ob = (size_t)(base + d) * 256 + lane;
        out_bf[ob]       = f2bf(eluf(a0 * rs.x + b0));
        out_bf[ob + 64]  = f2bf(eluf(a1 * rs.y + b1));
        out_bf[ob + 128] = f2bf(eluf(a2 * rs.z + b2));
        out_bf[ob + 192] = f2bf(eluf(a3 * rs.w + b3));
    }
}

// ---------------- fused tail: conv3 MFMA GEMM + logits + GAT agg + pool + head
__global__ void __launch_bounds__(512)
k_tail(const unsigned short* __restrict__ xb, const unsigned short* __restrict__ Wp3,
       const unsigned short* __restrict__ Mp3, const float* __restrict__ bias,
       const unsigned* __restrict__ csr, const int* __restrict__ noff,
       const int* __restrict__ cnt, const float* __restrict__ gin,
       const float* __restrict__ bn_g, const float* __restrict__ bn_b,
       const float* __restrict__ bn_m, const float* __restrict__ bn_v,
       const float* __restrict__ Wd1, const float* __restrict__ bd1,
       const float* __restrict__ Wd2, const float* __restrict__ bd2,
       const float* __restrict__ Wo, const float* __restrict__ bo,
       float* __restrict__ out){
    __shared__ __align__(16) unsigned short h3[NPG * 64];   // [n][c] bf16, 12.8 KB
    __shared__ __align__(16) unsigned int edl[EW_CAP][2];   // {w, sd} 11.3 KB
    __shared__ float asrcl[NPG], adstl[NPG];
    __shared__ float wselfl[NPG], rsuml[NPG];
    __shared__ int offl[NPG], cntl[NPG];
    __shared__ float red[8][64];
    __shared__ float gv[68], g2[64], g3[64];

    int g = blockIdx.x, t = threadIdx.x;
    int wave = t >> 6, lane = t & 63;
    int base = g * NPG;
    size_t ebeg = (size_t)g * EW_CAP;

    if (wave < 7){
        int quad = lane >> 4, ln = lane & 15;
        floatx4 acc[4];
        #pragma unroll
        for (int f = 0; f < 4; f++) acc[f] = (floatx4){0.f, 0.f, 0.f, 0.f};
        floatx4 accL = (floatx4){0.f, 0.f, 0.f, 0.f};
        const unsigned short* aptr = xb + (size_t)(base + wave * 16 + ln) * 256 + quad * 8;
        for (int kt = 0; kt < 256; kt += 32){
            short8 a = *(const short8*)(aptr + kt);
            int kc = (kt >> 3) + quad;
            #pragma unroll
            for (int f = 0; f < 4; f++){
                short8 bfr = *(const short8*)(Wp3 + ((size_t)kc * 64 + f * 16 + ln) * 8);
                acc[f] = __builtin_amdgcn_mfma_f32_16x16x32_bf16(a, bfr, acc[f], 0, 0, 0);
            }
            short8 m = *(const short8*)(Mp3 + ((size_t)kc * 16 + ln) * 8);
            accL = __builtin_amdgcn_mfma_f32_16x16x32_bf16(a, m, accL, 0, 0, 0);
        }
        int rowb = wave * 16 + quad * 4;
        #pragma unroll
        for (int f = 0; f < 4; f++){
            int col = f * 16 + ln;
            #pragma unroll
            for (int rg = 0; rg < 4; rg++){
                int row = rowb + rg;
                if (row < NPG) h3[row * 64 + col] = f2bf(acc[f][rg]);
            }
        }
        if (ln < 2){
            #pragma unroll
            for (int rg = 0; rg < 4; rg++){
                int row = rowb + rg;
                if (row < NPG){
                    if (ln == 0) asrcl[row] = accL[rg];
                    else         adstl[row] = accL[rg];
                }
            }
        }
    } else {
        for (int i = lane; i < NPG; i += 64){
            offl[i] = noff[base + i];
            cntl[i] = cnt[base + i];
        }
        int el = noff[base + NPG - 1] + cnt[base + NPG - 1];
        for (int i = lane; i < el; i += 64) edl[i][1] = csr[ebeg + i];
    }
    __syncthreads();
    int eln = offl[NPG - 1] + cntl[NPG - 1];

    for (int i = t; i < eln; i += 512){
        unsigned sd = edl[i][1];
        int s = sd & 0xFF, d = sd >> 8;
        edl[i][0] = (unsigned)f2bf(expf(lrelu(asrcl[s] + adstl[d])));
    }
    __syncthreads();

    if (t < NPG){
        float wsf = expf(lrelu(asrcl[t] + adstl[t]));
        float sum = wsf;
        int ebg = offl[t], n = cntl[t];
        for (int j = 0; j < n; j++) sum += bf2f((unsigned short)edl[ebg + j][0]);
        wselfl[t] = wsf;
        rsuml[t] = 1.f / sum;
    }
    __syncthreads();

    float bl = bias[lane];
    float pool = 0.f;
    for (int d = wave; d < NPG; d += 8){
        float acc = wselfl[d] * bf2f(h3[d * 64 + lane]);
        int ebg = offl[d], n = cntl[d];
        for (int j = 0; j < n; j++){
            uint2 v = *(const uint2*)&edl[ebg + j][0];
            acc = fmaf(bf2f_lo(v.x), bf2f(h3[(int)(v.y & 0xFFu) * 64 + lane]), acc);
        }
        pool += acc * rsuml[d] + bl;
    }
    red[wave][lane] = pool;
    __syncthreads();

    if (t < 64){
        float s = 0.f;
        #pragma unroll
        for (int i = 0; i < 8; i++) s += red[i][t];
        float mean = s * (1.f / 100.f);
        gv[t] = (mean - bn_m[t]) * rsqrtf(bn_v[t] + 1e-5f) * bn_g[t] + bn_b[t];
    } else if (t < 68){
        int j = t - 64;
        float v = gin[g * 4 + j];
        gv[t] = (v - bn_m[t]) * rsqrtf(bn_v[t] + 1e-5f) * bn_g[t] + bn_b[t];
    }
    __syncthreads();
    if (t < 64){
        float s = bd1[t];
        for (int i = 0; i < 68; i++) s += gv[i] * Wd1[i * 64 + t];
        g2[t] = seluf(s);
    }
    __syncthreads();
    if (t < 64){
        float s = bd2[t];
        for (int i = 0; i < 64; i++) s += g2[i] * Wd2[i * 64 + t];
        g3[t] = seluf(s);
    }
    __syncthreads();
    if (t == 0){
        float l0 = bo[0], l1 = bo[1];
        for (int i = 0; i < 64; i++){ l0 += g3[i] * Wo[i * 2]; l1 += g3[i] * Wo[i * 2 + 1]; }
        float mx = fmaxf(l0, l1);
        float e0 = expf(l0 - mx), e1 = expf(l1 - mx);
        float inv = 1.f / (e0 + e1);
        out[g * 2] = e0 * inv;
        out[g * 2 + 1] = e1 * inv;
    }
}

extern "C" void kernel_launch(void* const* d_in, const int* in_sizes, int n_in,
                              void* d_out, int out_size, void* d_ws, size_t ws_size,
                              hipStream_t stream){
    const float* x   = (const float*)d_in[0];
    const int*   ei  = (const int*)d_in[1];
    const float* gin = (const float*)d_in[2];
    const float* gn_w = (const float*)d_in[4];
    const float* gn_b = (const float*)d_in[5];
    const float* gn_ms = (const float*)d_in[6];
    const float* W1 = (const float*)d_in[7];
    const float* as1 = (const float*)d_in[8];
    const float* ad1 = (const float*)d_in[9];
    const float* b1 = (const float*)d_in[10];
    const float* W2 = (const float*)d_in[11];
    const float* as2 = (const float*)d_in[12];
    const float* ad2 = (const float*)d_in[13];
    const float* b2 = (const float*)d_in[14];
    const float* W3 = (const float*)d_in[15];
    const float* as3 = (const float*)d_in[16];
    const float* ad3 = (const float*)d_in[17];
    const float* b3 = (const float*)d_in[18];
    const float* bn_g = (const float*)d_in[19];
    const float* bn_b = (const float*)d_in[20];
    const float* bn_m = (const float*)d_in[21];
    const float* bn_v = (const float*)d_in[22];
    const float* Wd1 = (const float*)d_in[23];
    const float* bd1 = (const float*)d_in[24];
    const float* Wd2 = (const float*)d_in[25];
    const float* bd2 = (const float*)d_in[26];
    const float* Wo = (const float*)d_in[27];
    const float* bo = (const float*)d_in[28];
    float* out = (float*)d_out;

    const int* src = ei;
    const int* dst = ei + N_EDGES;

    char* ws = (char*)d_ws;
    size_t off = 0;
    auto alloc = [&](size_t bytes) -> void* {
        void* p = ws + off;
        off = (off + bytes + 255) & ~(size_t)255;
        return p;
    };
    int* counts     = (int*)alloc((size_t)N_NODES * 4);
    int* write_ptr  = (int*)alloc((size_t)N_NODES * 4);
    unsigned* csr   = (unsigned*)alloc((size_t)N_GRAPHS * EW_CAP * 4);
    int* noff       = (int*)alloc((size_t)N_NODES * 4);
    int* cnt        = (int*)alloc((size_t)N_NODES * 4);
    unsigned short* wp2 = (unsigned short*)alloc((size_t)256 * 256 * 2);
    unsigned short* wp3 = (unsigned short*)alloc((size_t)256 * 64 * 2);
    float* M1f      = (float*)alloc((size_t)16 * 8 * 4);
    unsigned short* Mp2 = (unsigned short*)alloc((size_t)32 * 16 * 8 * 2);
    unsigned short* Mp3 = (unsigned short*)alloc((size_t)32 * 16 * 8 * 2);
    float* lg1      = (float*)alloc((size_t)N_NODES * 8 * 4);
    unsigned short* xbh = (unsigned short*)alloc((size_t)N_ROWS_PAD * 256 * 2); // conv1 GEMM out (interleaved) / k_mid attention out (row-major)
    unsigned short* xb  = (unsigned short*)alloc((size_t)N_ROWS_PAD * 256 * 2); // fused4-conv1 out (row-major, k_mid GEMM A input)

    // --- CSR build (slab format, graph-local offsets; no global scan) ---
    hipMemsetAsync(counts, 0, (size_t)N_NODES * 4, stream);
    k_count<<<(N_EDGES + 255) / 256, 256, 0, stream>>>(dst, counts);
    k_prep<<<(90240 + 255) / 256, 256, 0, stream>>>(W1, as1, ad1, W2, as2, ad2,
                                                    W3, as3, ad3, wp2, wp3, M1f, Mp2, Mp3);
    k_local_scan<<<N_GRAPHS, 128, 0, stream>>>(counts, noff, cnt, write_ptr);
    k_scatter<<<(N_EDGES + 255) / 256, 256, 0, stream>>>(src, dst, write_ptr, csr);

    // --- GraphNorm + conv1 GEMM + conv1 logits (fused, one block/graph) ---
    k_gnorm_conv1<<<N_GRAPHS, 256, 0, stream>>>(x, gn_w, gn_b, gn_ms, W1, M1f, xbh, lg1);
    k_fused4<<<N_GRAPHS, 512, 0, stream>>>(xbh, lg1, b1, csr, noff, cnt, xb);

    // --- conv2 GEMM + logits + attention (fused, one block/graph) ---
    k_mid<<<N_GRAPHS, 512, 0, stream>>>(xb, wp2, Mp2, b2, csr, noff, cnt, xbh);

    // --- conv3 + GAT agg + pool + BN + dense head + softmax (one block/graph) ---
    k_tail<<<N_GRAPHS, 512, 0, stream>>>(xbh, wp3, Mp3, b3, csr, noff, cnt, gin,
                                         bn_g, bn_b, bn_m, bn_v,
                                         Wd1, bd1, Wd2, bd2, Wo, bo, out);
}